// Round 18
// baseline (59.993 us; speedup 1.0000x reference)
//
#include <hip/hip_runtime.h>

#define NV 100000
#define NJ 24
#define NP 207
#define NPART 25
#define GRIDF 2048
#define NWV (GRIDF * 4)        // 8192 waves; % 4 == 0 -> vertex&3 wave-constant

// ---------------------------------------------------------------------------
// DPP full-wave64 sum: row_shr 1/2/4/8 + row_bcast15 + row_bcast31.
// Lane 63 ends with the sum of all 64 lanes (bound_ctrl=1: OOB lanes add 0).
// ---------------------------------------------------------------------------
__device__ __forceinline__ float dpp_red64(float x) {
  x += __int_as_float(__builtin_amdgcn_update_dpp(0, __float_as_int(x), 0x111, 0xf, 0xf, true));
  x += __int_as_float(__builtin_amdgcn_update_dpp(0, __float_as_int(x), 0x112, 0xf, 0xf, true));
  x += __int_as_float(__builtin_amdgcn_update_dpp(0, __float_as_int(x), 0x114, 0xf, 0xf, true));
  x += __int_as_float(__builtin_amdgcn_update_dpp(0, __float_as_int(x), 0x118, 0xf, 0xf, true));
  x += __int_as_float(__builtin_amdgcn_update_dpp(0, __float_as_int(x), 0x142, 0xf, 0xf, true));
  x += __int_as_float(__builtin_amdgcn_update_dpp(0, __float_as_int(x), 0x143, 0xf, 0xf, true));
  return x;
}

// ---------------------------------------------------------------------------
// K1: v_shaped = v_template + shapedirs @ betas. 2 rows/thread, float4 loads.
// ---------------------------------------------------------------------------
__global__ __launch_bounds__(256) void k_shape(
    const float* __restrict__ betas, const float* __restrict__ v_template,
    const float* __restrict__ shapedirs, float* __restrict__ v_shaped) {
  __shared__ float sb[10];
  if (threadIdx.x < 10) sb[threadIdx.x] = betas[threadIdx.x];
  __syncthreads();
  int t = blockIdx.x * 256 + threadIdx.x;  // row-pair index
  if (t >= 3 * NV / 2) return;
  const float4* sd4 = (const float4*)(shapedirs + (size_t)t * 20);
  float4 f0 = sd4[0], f1 = sd4[1], f2 = sd4[2], f3 = sd4[3], f4v = sd4[4];
  float2 vt = ((const float2*)v_template)[t];
  float a = vt.x
          + f0.x * sb[0] + f0.y * sb[1] + f0.z * sb[2] + f0.w * sb[3]
          + f1.x * sb[4] + f1.y * sb[5] + f1.z * sb[6] + f1.w * sb[7]
          + f2.x * sb[8] + f2.y * sb[9];
  float b = vt.y
          + f2.z * sb[0] + f2.w * sb[1]
          + f3.x * sb[2] + f3.y * sb[3] + f3.z * sb[4] + f3.w * sb[5]
          + f4v.x * sb[6] + f4v.y * sb[7] + f4v.z * sb[8] + f4v.w * sb[9];
  ((float2*)v_shaped)[t] = make_float2(a, b);
}

// ---------------------------------------------------------------------------
// K2: J partials. grid = (24, 25), float4 loads, transposed jpT output.
// ---------------------------------------------------------------------------
__global__ __launch_bounds__(256) void k_jreg(
    const float* __restrict__ Jreg, const float* __restrict__ v_shaped,
    float* __restrict__ jpT) {
  int j = blockIdx.x, part = blockIdx.y, tid = threadIdx.x;
  const int SL = NV / NPART;  // 4000
  int v0 = part * SL;
  const float4* w4 = (const float4*)(Jreg + (size_t)j * NV + v0);
  const float4* s4 = (const float4*)(v_shaped + (size_t)3 * v0);
  float s0 = 0.f, s1 = 0.f, s2 = 0.f;
  for (int i4 = tid; i4 < SL / 4; i4 += 256) {
    float4 w = w4[i4];
    float4 A = s4[3 * i4 + 0];
    float4 B = s4[3 * i4 + 1];
    float4 C = s4[3 * i4 + 2];
    s0 += w.x * A.x + w.y * A.w + w.z * B.z + w.w * C.y;
    s1 += w.x * A.y + w.y * B.x + w.z * B.w + w.w * C.z;
    s2 += w.x * A.z + w.y * B.y + w.z * C.x + w.w * C.w;
  }
  __shared__ float red[256][3];
  red[tid][0] = s0; red[tid][1] = s1; red[tid][2] = s2;
  __syncthreads();
  for (int off = 128; off > 0; off >>= 1) {
    if (tid < off) {
      red[tid][0] += red[tid + off][0];
      red[tid][1] += red[tid + off][1];
      red[tid][2] += red[tid + off][2];
    }
    __syncthreads();
  }
  if (tid < 3) jpT[(j * 3 + tid) * 32 + part] = red[0][tid];
}

// ---------------------------------------------------------------------------
// Stage one vertex window (156 float4) into this wave's LDS buffer.
// Rounds 0,1 full-wave; round 2 exec-masked to lane<28 (masked lanes do not
// write -- verified empirically by R6-style staging). Source is the vertex
// row rounded DOWN to a float4 boundary; the +<=3-float shift is wave-
// constant (NWV % 4 == 0) and folded into the compute row pointer.
// ---------------------------------------------------------------------------
__device__ __forceinline__ void stage_vert(float4* dst, const float4* src, int lane) {
  __builtin_amdgcn_global_load_lds(
      (const __attribute__((address_space(1))) void*)(src + lane),
      (__attribute__((address_space(3))) void*)(dst), 16, 0, 0);
  __builtin_amdgcn_global_load_lds(
      (const __attribute__((address_space(1))) void*)(src + 64 + lane),
      (__attribute__((address_space(3))) void*)(dst + 64), 16, 0, 0);
  if (lane < 28) {
    __builtin_amdgcn_global_load_lds(
        (const __attribute__((address_space(1))) void*)(src + 128 + lane),
        (__attribute__((address_space(3))) void*)(dst + 128), 16, 0, 0);
  }
}

__device__ __forceinline__ const float4* vert_src(const float* posedirs, int v) {
  size_t startf = (size_t)1863 * v / 3;  // dummy-proof? no -- see below
  return (const float4*)(posedirs + ((size_t)621 * v - (v & 3)));
}

// ---------------------------------------------------------------------------
// K3: fused FK + pose-blend + LBS, barrier-free per-wave pipeline at FULL
// occupancy: 1 vertex/wave, buf[4][2][160] = 20480 B/block -> 8 blocks/CU
// = 32 waves/CU. Per iter: 2 scalar prefetches + 3 stage ops -> vmcnt(5)
// drains exactly the previous iter's 5 (one full iteration old -> no stall).
// 64-lane dot + full-wave DPP reduce (sum in lane 63).
// ---------------------------------------------------------------------------
__global__ __launch_bounds__(256, 8) void k_fused(
    const float* __restrict__ posedirs, const float* __restrict__ wgt,
    const float* __restrict__ pose, const float* __restrict__ jpT,
    const float* __restrict__ scale, const float* __restrict__ trans,
    float* __restrict__ vbuf) {
  __shared__ float4 buf[4][2][160];   // 20480 B = 8 blocks/CU exactly
  int tid = threadIdx.x, b = blockIdx.x;
  int wid = tid >> 6, lane = tid & 63;
  int W = b * 4 + wid;                // wave id 0..8191
  int sh = W & 3;                     // vertex&3 == W&3 (NWV % 4 == 0)

  // P_0 scalars + S_0 stage for vertex W
  float pvl = (lane < 3) ? vbuf[(size_t)3 * W + lane] : 0.f;
  float wj  = (lane < NJ) ? wgt[(size_t)W * NJ + lane] : 0.f;
  __builtin_amdgcn_sched_barrier(0);
  stage_vert(&buf[wid][0][0], vert_src(posedirs, W), lane);

  // ---- FK scratch: buf[0][1] (495 fl) + buf[1][1] (576 fl), both dead
  //      until loop-iter 0 stages them (after the final pre-loop sync) ----
  float* fkJ  = (float*)&buf[0][1][0];  // [72]
  float* fkR  = fkJ + 72;               // [216]
  float* lrs  = fkJ + 288;              // [207]   (495 <= 640)
  float* fkG  = (float*)&buf[1][1][0];  // [288]
  float* relS = fkG + 288;              // [288]   (576 <= 640)
  if (tid < NJ * 3) {
    const float* src = jpT + tid * 32;
    float a = 0.f;
    #pragma unroll
    for (int i = 0; i < NPART; ++i) a += src[i];
    fkJ[tid] = a;
  }
  if (tid < NJ) {
    float rx = pose[tid * 3 + 0], ry = pose[tid * 3 + 1], rz = pose[tid * 3 + 2];
    float tx = rx + 1e-8f, ty = ry + 1e-8f, tz = rz + 1e-8f;
    float theta = sqrtf(tx * tx + ty * ty + tz * tz);
    float x = rx / theta, y = ry / theta, z = rz / theta;
    float c = cosf(theta), s = sinf(theta), C = 1.f - c;
    float Rr[9];
    Rr[0] = c + C * x * x;     Rr[1] = C * x * y - s * z; Rr[2] = C * x * z + s * y;
    Rr[3] = C * x * y + s * z; Rr[4] = c + C * y * y;     Rr[5] = C * y * z - s * x;
    Rr[6] = C * x * z - s * y; Rr[7] = C * y * z + s * x; Rr[8] = c + C * z * z;
    #pragma unroll
    for (int e = 0; e < 9; ++e) fkR[tid * 9 + e] = Rr[e];
    if (tid >= 1) {
      #pragma unroll
      for (int e = 0; e < 9; ++e) {
        float id = (e == 0 || e == 4 || e == 8) ? 1.f : 0.f;
        lrs[(tid - 1) * 9 + e] = Rr[e] - id;
      }
    }
  }
  __syncthreads();
  if (tid < 3) {  // row-parallel chain: lane a owns row a of all G_i
    const int par[NJ] = {-1,0,0,0,1,2,3,4,5,6,7,8,9,9,9,12,13,14,16,17,18,19,20,21};
    int a = tid;
    fkG[a * 4 + 0] = fkR[a * 3 + 0];
    fkG[a * 4 + 1] = fkR[a * 3 + 1];
    fkG[a * 4 + 2] = fkR[a * 3 + 2];
    fkG[a * 4 + 3] = fkJ[a];
    #pragma unroll
    for (int i = 1; i < NJ; ++i) {
      int p = par[i];
      float t0 = fkJ[i * 3 + 0] - fkJ[p * 3 + 0];
      float t1 = fkJ[i * 3 + 1] - fkJ[p * 3 + 1];
      float t2 = fkJ[i * 3 + 2] - fkJ[p * 3 + 2];
      float g0 = fkG[p * 12 + a * 4 + 0], g1 = fkG[p * 12 + a * 4 + 1];
      float g2 = fkG[p * 12 + a * 4 + 2], g3 = fkG[p * 12 + a * 4 + 3];
      fkG[i * 12 + a * 4 + 0] = g0 * fkR[i * 9 + 0] + g1 * fkR[i * 9 + 3] + g2 * fkR[i * 9 + 6];
      fkG[i * 12 + a * 4 + 1] = g0 * fkR[i * 9 + 1] + g1 * fkR[i * 9 + 4] + g2 * fkR[i * 9 + 7];
      fkG[i * 12 + a * 4 + 2] = g0 * fkR[i * 9 + 2] + g1 * fkR[i * 9 + 5] + g2 * fkR[i * 9 + 8];
      fkG[i * 12 + a * 4 + 3] = g3 + g0 * t0 + g1 * t1 + g2 * t2;
    }
  }
  __syncthreads();
  if (tid < NJ) {
    #pragma unroll
    for (int a = 0; a < 3; ++a) {
      float corr = fkG[tid * 12 + a * 4 + 0] * fkJ[tid * 3 + 0] +
                   fkG[tid * 12 + a * 4 + 1] * fkJ[tid * 3 + 1] +
                   fkG[tid * 12 + a * 4 + 2] * fkJ[tid * 3 + 2];
      relS[tid * 12 + a * 4 + 0] = fkG[tid * 12 + a * 4 + 0];
      relS[tid * 12 + a * 4 + 1] = fkG[tid * 12 + a * 4 + 1];
      relS[tid * 12 + a * 4 + 2] = fkG[tid * 12 + a * 4 + 2];
      relS[tid * 12 + a * 4 + 3] = fkG[tid * 12 + a * 4 + 3] - corr;
    }
  }
  __syncthreads();

  float llr[4];
  #pragma unroll
  for (int e = 0; e < 4; ++e) {
    int p = lane + 64 * e;
    llr[e] = (p < NP) ? lrs[p] : 0.f;
  }
  float rlq[12];
  #pragma unroll
  for (int e = 0; e < 12; ++e) rlq[e] = (lane < NJ) ? relS[lane * 12 + e] : 0.f;
  float sc = scale[0];
  float tr = (lane < 3) ? trans[lane] : 0.f;

  __syncthreads();  // scratch reads done; buf[0/1][1] may be staged from now on
  asm volatile("s_waitcnt vmcnt(0)" ::: "memory");  // clean per-wave base

  int nt = (NV - 1 - W) / NWV + 1;  // per-wave trip count (12 or 13)
  for (int it = 0; it < nt; ++it) {
    int cur = it & 1;
    int vn = W + (it + 1) * NWV;
    if (vn >= NV) vn = NV - 1;  // dummy on last iter (never read)
    float pvl_n = (lane < 3) ? vbuf[(size_t)3 * vn + lane] : 0.f;
    float wj_n  = (lane < NJ) ? wgt[(size_t)vn * NJ + lane] : 0.f;
    __builtin_amdgcn_sched_barrier(0);
    stage_vert(&buf[wid][cur ^ 1][0], vert_src(posedirs, vn), lane);
    asm volatile("s_waitcnt vmcnt(5)" ::: "memory");
    __builtin_amdgcn_sched_barrier(0);

    int v = W + it * NWV;
    const float* row = (const float*)&buf[wid][cur][0] + sh;
    float a0 = 0.f, a1 = 0.f, a2 = 0.f;
    #pragma unroll
    for (int e = 0; e < 4; ++e) {
      int p = lane + 64 * e;
      if (p < NP) {
        float l = llr[e];
        a0 += row[p] * l;
        a1 += row[NP + p] * l;
        a2 += row[2 * NP + p] * l;
      }
    }
    a0 = __shfl(dpp_red64(a0), 63);
    a1 = __shfl(dpp_red64(a1), 63);
    a2 = __shfl(dpp_red64(a2), 63);
    float p0 = __shfl(pvl, 0) + a0;
    float p1 = __shfl(pvl, 1) + a1;
    float p2 = __shfl(pvl, 2) + a2;
    float q0v = rlq[0] * p0 + rlq[1] * p1 + rlq[2]  * p2 + rlq[3];
    float q1v = rlq[4] * p0 + rlq[5] * p1 + rlq[6]  * p2 + rlq[7];
    float q2v = rlq[8] * p0 + rlq[9] * p1 + rlq[10] * p2 + rlq[11];
    float r0 = __shfl(dpp_red64(wj * q0v), 63);
    float r1 = __shfl(dpp_red64(wj * q1v), 63);
    float r2 = __shfl(dpp_red64(wj * q2v), 63);
    if (lane < 3) {
      float oo = (lane == 0) ? r0 : (lane == 1) ? r1 : r2;
      vbuf[(size_t)3 * v + lane] = oo * sc + tr;
    }
    pvl = pvl_n; wj = wj_n;
  }
  asm volatile("s_waitcnt vmcnt(0)" ::: "memory");  // drain tail dummies
}

extern "C" void kernel_launch(void* const* d_in, const int* in_sizes, int n_in,
                              void* d_out, int out_size, void* d_ws, size_t ws_size,
                              hipStream_t stream) {
  const float* betas      = (const float*)d_in[0];
  const float* pose       = (const float*)d_in[1];
  const float* scale      = (const float*)d_in[2];
  const float* trans      = (const float*)d_in[3];
  const float* v_template = (const float*)d_in[4];
  const float* shapedirs  = (const float*)d_in[5];
  const float* posedirs   = (const float*)d_in[6];
  const float* Jreg       = (const float*)d_in[7];
  const float* weights    = (const float*)d_in[8];
  float* out = (float*)d_out;
  float* ws  = (float*)d_ws;

  float* jpT = ws;  // 72*32 = 2304 floats

  k_shape<<<(3 * NV / 2 + 255) / 256, 256, 0, stream>>>(betas, v_template, shapedirs, out);
  k_jreg<<<dim3(NJ, NPART), 256, 0, stream>>>(Jreg, out, jpT);
  k_fused<<<GRIDF, 256, 0, stream>>>(posedirs, weights, pose, jpT, scale, trans, out);
}

// Round 19
// 58.729 us; speedup vs baseline: 1.0215x; 1.0215x over previous
//
#include <hip/hip_runtime.h>

#define NV 100000
#define NJ 24
#define NP 207
#define NPART 25
#define NPAIRS (NV / 2)        // 50000 2-vertex pairs
#define GRIDF 1024
#define NWV (GRIDF * 4)        // 4096 waves (even -> pair parity = W parity)

// ---------------------------------------------------------------------------
// DPP 32-lane-group sum (VALU pipe). Lane 31 holds sum(0..31), 63 sum(32..63).
// ---------------------------------------------------------------------------
__device__ __forceinline__ float dpp_red32(float x) {
  x += __int_as_float(__builtin_amdgcn_update_dpp(0, __float_as_int(x), 0x111, 0xf, 0xf, true));
  x += __int_as_float(__builtin_amdgcn_update_dpp(0, __float_as_int(x), 0x112, 0xf, 0xf, true));
  x += __int_as_float(__builtin_amdgcn_update_dpp(0, __float_as_int(x), 0x114, 0xf, 0xf, true));
  x += __int_as_float(__builtin_amdgcn_update_dpp(0, __float_as_int(x), 0x118, 0xf, 0xf, true));
  x += __int_as_float(__builtin_amdgcn_update_dpp(0, __float_as_int(x), 0x142, 0xf, 0xf, true));
  return x;
}

// ---------------------------------------------------------------------------
// K1: v_shaped = v_template + shapedirs @ betas. 2 rows/thread, float4 loads.
// ---------------------------------------------------------------------------
__global__ __launch_bounds__(256) void k_shape(
    const float* __restrict__ betas, const float* __restrict__ v_template,
    const float* __restrict__ shapedirs, float* __restrict__ v_shaped) {
  __shared__ float sb[10];
  if (threadIdx.x < 10) sb[threadIdx.x] = betas[threadIdx.x];
  __syncthreads();
  int t = blockIdx.x * 256 + threadIdx.x;  // row-pair index
  if (t >= 3 * NV / 2) return;
  const float4* sd4 = (const float4*)(shapedirs + (size_t)t * 20);
  float4 f0 = sd4[0], f1 = sd4[1], f2 = sd4[2], f3 = sd4[3], f4v = sd4[4];
  float2 vt = ((const float2*)v_template)[t];
  float a = vt.x
          + f0.x * sb[0] + f0.y * sb[1] + f0.z * sb[2] + f0.w * sb[3]
          + f1.x * sb[4] + f1.y * sb[5] + f1.z * sb[6] + f1.w * sb[7]
          + f2.x * sb[8] + f2.y * sb[9];
  float b = vt.y
          + f2.z * sb[0] + f2.w * sb[1]
          + f3.x * sb[2] + f3.y * sb[3] + f3.z * sb[4] + f3.w * sb[5]
          + f4v.x * sb[6] + f4v.y * sb[7] + f4v.z * sb[8] + f4v.w * sb[9];
  ((float2*)v_shaped)[t] = make_float2(a, b);
}

// ---------------------------------------------------------------------------
// K2: J partials. grid = (24, 25), float4 loads, transposed jpT output.
// ---------------------------------------------------------------------------
__global__ __launch_bounds__(256) void k_jreg(
    const float* __restrict__ Jreg, const float* __restrict__ v_shaped,
    float* __restrict__ jpT) {
  int j = blockIdx.x, part = blockIdx.y, tid = threadIdx.x;
  const int SL = NV / NPART;  // 4000
  int v0 = part * SL;
  const float4* w4 = (const float4*)(Jreg + (size_t)j * NV + v0);
  const float4* s4 = (const float4*)(v_shaped + (size_t)3 * v0);
  float s0 = 0.f, s1 = 0.f, s2 = 0.f;
  for (int i4 = tid; i4 < SL / 4; i4 += 256) {
    float4 w = w4[i4];
    float4 A = s4[3 * i4 + 0];
    float4 B = s4[3 * i4 + 1];
    float4 C = s4[3 * i4 + 2];
    s0 += w.x * A.x + w.y * A.w + w.z * B.z + w.w * C.y;
    s1 += w.x * A.y + w.y * B.x + w.z * B.w + w.w * C.z;
    s2 += w.x * A.z + w.y * B.y + w.z * C.x + w.w * C.w;
  }
  __shared__ float red[256][3];
  red[tid][0] = s0; red[tid][1] = s1; red[tid][2] = s2;
  __syncthreads();
  for (int off = 128; off > 0; off >>= 1) {
    if (tid < off) {
      red[tid][0] += red[tid + off][0];
      red[tid][1] += red[tid + off][1];
      red[tid][2] += red[tid + off][2];
    }
    __syncthreads();
  }
  if (tid < 3) jpT[(j * 3 + tid) * 32 + part] = red[0][tid];
}

// ---------------------------------------------------------------------------
// Stage one 2-vertex pair window (311 float4, dest padded to 320) into this
// wave's LDS buffer. Src is the pair's float range rounded DOWN to a float4
// boundary (always 16B-aligned); odd pairs carry a +2-float LDS offset,
// folded into the (wave-constant) row pointer. Clamped tail; pad absorbs.
// ---------------------------------------------------------------------------
__device__ __forceinline__ void stage_pair(float4* dst, const float4* src, int lane) {
  #pragma unroll
  for (int r = 0; r < 5; ++r) {
    int i4 = r * 64 + lane;
    int i4c = (i4 < 311) ? i4 : 310;
    __builtin_amdgcn_global_load_lds(
        (const __attribute__((address_space(1))) void*)(src + i4c),
        (__attribute__((address_space(3))) void*)(dst + r * 64),
        16, 0, 0);
  }
}

__device__ __forceinline__ const float4* pair_src(const float* posedirs, int p) {
  size_t startf = (size_t)1242 * p - ((p & 1) ? 2 : 0);  // multiple of 4
  return (const float4*)(posedirs + startf);
}

// ---------------------------------------------------------------------------
// K3: fused FK + pose-blend + LBS, barrier-free per-wave pipeline.
// Chunk = 2-vertex pair -> 10KB LDS/wave -> 4 blocks/CU = 16 waves/CU
// (measured optimum: 8/16/32 waves/CU = 59.8/58.0/60.0 us). Per iter:
// 2 scalar prefetches + 5 stage ops -> vmcnt(7) drains exactly the previous
// iter's 7 (a full iteration old -> no stall) -> one 2-vertex compute pass.
// ---------------------------------------------------------------------------
__global__ __launch_bounds__(256, 4) void k_fused(
    const float* __restrict__ posedirs, const float* __restrict__ wgt,
    const float* __restrict__ pose, const float* __restrict__ jpT,
    const float* __restrict__ scale, const float* __restrict__ trans,
    float* __restrict__ vbuf) {
  __shared__ float4 buf[4][2][320];   // 40960 B = 4 blocks/CU exactly
  int tid = threadIdx.x, b = blockIdx.x;
  int wid = tid >> 6, lane = tid & 63, half = lane >> 5, lj = lane & 31;
  int W = b * 4 + wid;                // wave id 0..4095
  int sh = (W & 1) ? 2 : 0;           // pair parity == W parity (NWV even)

  // P_0 scalars + S_0 stage for pair W
  float pvl = (lj < 3) ? vbuf[(size_t)3 * (W * 2 + half) + lj] : 0.f;
  float wj  = (lj < NJ) ? wgt[(size_t)(W * 2 + half) * NJ + lj] : 0.f;
  __builtin_amdgcn_sched_barrier(0);
  stage_pair(&buf[wid][0][0], pair_src(posedirs, W), lane);

  // ---- FK in buf[0][1] scratch (staged only at iter 0, after final sync) ----
  float* fkJ  = (float*)&buf[0][1][0];  // [24*3]
  float* fkR  = fkJ + 72;               // [24*9]
  float* fkG  = fkJ + 288;              // [24*12]
  float* lrs  = fkJ + 576;              // [207]
  float* relS = fkJ + 784;              // [24*12]  (total 1072 fl = 4288 B <= 5120)
  if (tid < NJ * 3) {
    const float* src = jpT + tid * 32;
    float a = 0.f;
    #pragma unroll
    for (int i = 0; i < NPART; ++i) a += src[i];
    fkJ[tid] = a;
  }
  if (tid < NJ) {
    float rx = pose[tid * 3 + 0], ry = pose[tid * 3 + 1], rz = pose[tid * 3 + 2];
    float tx = rx + 1e-8f, ty = ry + 1e-8f, tz = rz + 1e-8f;
    float theta = sqrtf(tx * tx + ty * ty + tz * tz);
    float x = rx / theta, y = ry / theta, z = rz / theta;
    float c = cosf(theta), s = sinf(theta), C = 1.f - c;
    float Rr[9];
    Rr[0] = c + C * x * x;     Rr[1] = C * x * y - s * z; Rr[2] = C * x * z + s * y;
    Rr[3] = C * x * y + s * z; Rr[4] = c + C * y * y;     Rr[5] = C * y * z - s * x;
    Rr[6] = C * x * z - s * y; Rr[7] = C * y * z + s * x; Rr[8] = c + C * z * z;
    #pragma unroll
    for (int e = 0; e < 9; ++e) fkR[tid * 9 + e] = Rr[e];
    if (tid >= 1) {
      #pragma unroll
      for (int e = 0; e < 9; ++e) {
        float id = (e == 0 || e == 4 || e == 8) ? 1.f : 0.f;
        lrs[(tid - 1) * 9 + e] = Rr[e] - id;
      }
    }
  }
  __syncthreads();
  if (tid < 3) {  // row-parallel chain: lane a owns row a of all G_i
    const int par[NJ] = {-1,0,0,0,1,2,3,4,5,6,7,8,9,9,9,12,13,14,16,17,18,19,20,21};
    int a = tid;
    fkG[a * 4 + 0] = fkR[a * 3 + 0];
    fkG[a * 4 + 1] = fkR[a * 3 + 1];
    fkG[a * 4 + 2] = fkR[a * 3 + 2];
    fkG[a * 4 + 3] = fkJ[a];
    #pragma unroll
    for (int i = 1; i < NJ; ++i) {
      int p = par[i];
      float t0 = fkJ[i * 3 + 0] - fkJ[p * 3 + 0];
      float t1 = fkJ[i * 3 + 1] - fkJ[p * 3 + 1];
      float t2 = fkJ[i * 3 + 2] - fkJ[p * 3 + 2];
      float g0 = fkG[p * 12 + a * 4 + 0], g1 = fkG[p * 12 + a * 4 + 1];
      float g2 = fkG[p * 12 + a * 4 + 2], g3 = fkG[p * 12 + a * 4 + 3];
      fkG[i * 12 + a * 4 + 0] = g0 * fkR[i * 9 + 0] + g1 * fkR[i * 9 + 3] + g2 * fkR[i * 9 + 6];
      fkG[i * 12 + a * 4 + 1] = g0 * fkR[i * 9 + 1] + g1 * fkR[i * 9 + 4] + g2 * fkR[i * 9 + 7];
      fkG[i * 12 + a * 4 + 2] = g0 * fkR[i * 9 + 2] + g1 * fkR[i * 9 + 5] + g2 * fkR[i * 9 + 8];
      fkG[i * 12 + a * 4 + 3] = g3 + g0 * t0 + g1 * t1 + g2 * t2;
    }
  }
  __syncthreads();
  if (tid < NJ) {
    #pragma unroll
    for (int a = 0; a < 3; ++a) {
      float corr = fkG[tid * 12 + a * 4 + 0] * fkJ[tid * 3 + 0] +
                   fkG[tid * 12 + a * 4 + 1] * fkJ[tid * 3 + 1] +
                   fkG[tid * 12 + a * 4 + 2] * fkJ[tid * 3 + 2];
      relS[tid * 12 + a * 4 + 0] = fkG[tid * 12 + a * 4 + 0];
      relS[tid * 12 + a * 4 + 1] = fkG[tid * 12 + a * 4 + 1];
      relS[tid * 12 + a * 4 + 2] = fkG[tid * 12 + a * 4 + 2];
      relS[tid * 12 + a * 4 + 3] = fkG[tid * 12 + a * 4 + 3] - corr;
    }
  }
  __syncthreads();

  float llr[7];
  #pragma unroll
  for (int e = 0; e < 7; ++e) {
    int p = lj + 32 * e;
    llr[e] = (p < NP) ? lrs[p] : 0.f;
  }
  float rlq[12];
  #pragma unroll
  for (int e = 0; e < 12; ++e) rlq[e] = (lj < NJ) ? relS[lj * 12 + e] : 0.f;
  float sc = scale[0];
  float tr = (lj < 3) ? trans[lj] : 0.f;

  __syncthreads();  // scratch reads done; buf[0][1] may be staged from now on
  asm volatile("s_waitcnt vmcnt(0)" ::: "memory");  // clean per-wave base

  int nt = (NPAIRS - 1 - W) / NWV + 1;  // per-wave trip count
  for (int it = 0; it < nt; ++it) {
    int cur = it & 1;
    int pn = W + (it + 1) * NWV;
    if (pn >= NPAIRS) pn = NPAIRS - 1;  // dummy on last iter (same parity)
    float pvl_n = (lj < 3) ? vbuf[(size_t)3 * (pn * 2 + half) + lj] : 0.f;
    float wj_n  = (lj < NJ) ? wgt[(size_t)(pn * 2 + half) * NJ + lj] : 0.f;
    __builtin_amdgcn_sched_barrier(0);
    stage_pair(&buf[wid][cur ^ 1][0], pair_src(posedirs, pn), lane);
    asm volatile("s_waitcnt vmcnt(7)" ::: "memory");
    __builtin_amdgcn_sched_barrier(0);

    int p = W + it * NWV;
    int vv = p * 2 + half;
    const float* row = (const float*)&buf[wid][cur][0] + sh + half * (3 * NP);
    float a0 = 0.f, a1 = 0.f, a2 = 0.f;
    #pragma unroll
    for (int e = 0; e < 7; ++e) {
      int pp = lj + 32 * e;
      if (pp < NP) {
        float l = llr[e];
        a0 += row[pp] * l;
        a1 += row[NP + pp] * l;
        a2 += row[2 * NP + pp] * l;
      }
    }
    int gb = lane & 32;
    a0 = __shfl(dpp_red32(a0), gb + 31);
    a1 = __shfl(dpp_red32(a1), gb + 31);
    a2 = __shfl(dpp_red32(a2), gb + 31);
    float p0 = __shfl(pvl, gb + 0) + a0;
    float p1 = __shfl(pvl, gb + 1) + a1;
    float p2 = __shfl(pvl, gb + 2) + a2;
    float q0v = rlq[0] * p0 + rlq[1] * p1 + rlq[2]  * p2 + rlq[3];
    float q1v = rlq[4] * p0 + rlq[5] * p1 + rlq[6]  * p2 + rlq[7];
    float q2v = rlq[8] * p0 + rlq[9] * p1 + rlq[10] * p2 + rlq[11];
    float r0 = __shfl(dpp_red32(wj * q0v), gb + 31);
    float r1 = __shfl(dpp_red32(wj * q1v), gb + 31);
    float r2 = __shfl(dpp_red32(wj * q2v), gb + 31);
    if (lj < 3) {
      float oo = (lj == 0) ? r0 : (lj == 1) ? r1 : r2;
      vbuf[(size_t)3 * vv + lj] = oo * sc + tr;
    }
    pvl = pvl_n; wj = wj_n;
  }
  asm volatile("s_waitcnt vmcnt(0)" ::: "memory");  // drain tail dummies
}

extern "C" void kernel_launch(void* const* d_in, const int* in_sizes, int n_in,
                              void* d_out, int out_size, void* d_ws, size_t ws_size,
                              hipStream_t stream) {
  const float* betas      = (const float*)d_in[0];
  const float* pose       = (const float*)d_in[1];
  const float* scale      = (const float*)d_in[2];
  const float* trans      = (const float*)d_in[3];
  const float* v_template = (const float*)d_in[4];
  const float* shapedirs  = (const float*)d_in[5];
  const float* posedirs   = (const float*)d_in[6];
  const float* Jreg       = (const float*)d_in[7];
  const float* weights    = (const float*)d_in[8];
  float* out = (float*)d_out;
  float* ws  = (float*)d_ws;

  float* jpT = ws;  // 72*32 = 2304 floats

  k_shape<<<(3 * NV / 2 + 255) / 256, 256, 0, stream>>>(betas, v_template, shapedirs, out);
  k_jreg<<<dim3(NJ, NPART), 256, 0, stream>>>(Jreg, out, jpT);
  k_fused<<<GRIDF, 256, 0, stream>>>(posedirs, weights, pose, jpT, scale, trans, out);
}